// Round 2
// baseline (4457.477 us; speedup 1.0000x reference)
//
#include <hip/hip_runtime.h>
#include <stdint.h>

// HistMatching via stable LSD radix sort (4 x 8-bit passes) of (key32,idx32)
// u64 pairs per segment. Stability via per-(bin,block) histogram matrix +
// exclusive scan (no per-element global atomics on pair data). Final pass
// fuses the epilogue: template -> tsorted[dest]=val; samples ->
// out[idx]=tsorted[dest].
//
// R1: part_k single-LDS-buffer in-place split (occupancy 2->4 blocks/CU),
//     run-boundary starts instead of LDS-atomic hist, hoisted base gather.
// R2: hist_k ELIMINATED. part_k pass p accumulates the pass-(p+1) histogram
//     itself: it already knows each element's destination dest, so it
//     atomicAdds (nextDigit, dest/TILE) directly in scan-order [bin][blk]
//     layout (exact & order-independent => deterministic). Hkb is reused as
//     the ping-pong partner of Hbk; zeroing of the accumulation target is
//     folded into scan_a_k (stream-ordered between last consumer and next
//     producer). Saves 3 full 189MB re-reads + 3 transposes per group.

#define SEG_N 2621440            // 128*160*128
#define NSEG 9                   // template + 8 samples
#define TILE 4096
#define NBLK (SEG_N / TILE)      // 640 blocks per segment
#define RADIX 256
#define HL (RADIX * NBLK)        // 163840 histogram-matrix entries per seg
#define SCHUNK 4096
#define SNB (HL / SCHUNK)        // 40 scan blocks per seg
#define SBUF (TILE + (TILE >> 4))  // 4352 u64, padded 1-per-16

// monotone f32 -> u32 (order-preserving)
__device__ __forceinline__ uint32_t fkey(float f) {
  uint32_t b = __float_as_uint(f);
  return b ^ ((b & 0x80000000u) ? 0xFFFFFFFFu : 0x80000000u);
}
__device__ __forceinline__ float finv(uint32_t u) {
  uint32_t b = u ^ ((u & 0x80000000u) ? 0x80000000u : 0xFFFFFFFFu);
  return __uint_as_float(b);
}
__device__ __forceinline__ uint32_t SIDX(uint32_t i) { return i + (i >> 4); }

// ---------- init: build pairsA in index order + digit-0 histogram ----------
__global__ __launch_bounds__(256) void init_k(const float* __restrict__ x,
                                              const float* __restrict__ tmpl,
                                              int segbase,
                                              uint64_t* __restrict__ pairsA,
                                              uint32_t* __restrict__ Hkb) {
  __shared__ uint32_t hist[RADIX];
  const int t = threadIdx.x;
  const int blk = blockIdx.x;
  const int sl = blockIdx.y;
  const int seg = segbase + sl;
  const float* src = (seg == 0) ? tmpl : (x + (size_t)(seg - 1) * SEG_N);
  uint64_t* pa = pairsA + (size_t)sl * SEG_N;
  hist[t] = 0;
  __syncthreads();
  const uint32_t base = blk * TILE;
  const float4* s4 = reinterpret_cast<const float4*>(src + base);
#pragma unroll
  for (int r = 0; r < 4; ++r) {
    float4 v = s4[r * 256 + t];
    uint32_t i0 = base + (uint32_t)(r * 256 + t) * 4u;
    float f[4] = {v.x, v.y, v.z, v.w};
#pragma unroll
    for (int c = 0; c < 4; ++c) {
      uint32_t k = fkey(f[c]);
      atomicAdd(&hist[k & 255u], 1u);
      pa[i0 + c] = ((uint64_t)k << 32) | (uint64_t)(i0 + c);
    }
  }
  __syncthreads();
  Hkb[(size_t)sl * HL + (size_t)blk * RADIX + t] = hist[t];  // [blk][bin]
}

// ---------- transpose [blk][bin] -> [bin][blk] (pass 0 only) ----------
__global__ __launch_bounds__(256) void transp_k(const uint32_t* __restrict__ Hkb,
                                                uint32_t* __restrict__ Hbk) {
  __shared__ uint32_t tile[64][65];
  const int sl = blockIdx.y;
  const uint32_t* src = Hkb + (size_t)sl * HL;
  uint32_t* dst = Hbk + (size_t)sl * HL;
  const int kt = blockIdx.x % (NBLK / 64);  // 10 k-tiles
  const int bt = blockIdx.x / (NBLK / 64);  // 4 b-tiles
  const int tx = threadIdx.x & 63, ty = threadIdx.x >> 6;
#pragma unroll
  for (int r = 0; r < 16; ++r) {
    int k = kt * 64 + ty + r * 4;
    tile[ty + r * 4][tx] = src[(size_t)k * RADIX + bt * 64 + tx];
  }
  __syncthreads();
#pragma unroll
  for (int r = 0; r < 16; ++r) {
    int b = bt * 64 + ty + r * 4;
    dst[(size_t)b * NBLK + kt * 64 + tx] = tile[tx][ty + r * 4];
  }
}

// ---------- 3-level exclusive scan over counts (length HL per seg) ----------
__device__ __forceinline__ uint32_t block_excl_scan_256(uint32_t v, uint32_t* lds) {
  const int t = threadIdx.x;
  lds[t] = v;
  __syncthreads();
#pragma unroll
  for (int off = 1; off < 256; off <<= 1) {
    uint32_t a = (t >= off) ? lds[t - off] : 0u;
    __syncthreads();
    lds[t] += a;
    __syncthreads();
  }
  uint32_t ex = (t == 0) ? 0u : lds[t - 1];
  __syncthreads();
  return ex;
}

// scan_a also zeroes the NEXT pass's accumulation buffer (zbuf), which by
// stream order is dead (its last consumer, the previous part_k, completed).
__global__ __launch_bounds__(256) void scan_a_k(const uint32_t* __restrict__ cnt,
                                                uint32_t* __restrict__ partials,
                                                uint32_t* __restrict__ zbuf) {
  __shared__ uint32_t lds[256];
  const int t = threadIdx.x;
  const size_t boff = (size_t)blockIdx.y * HL + (size_t)blockIdx.x * SCHUNK +
                      (size_t)t * 16;
  const uint4* p = reinterpret_cast<const uint4*>(cnt + boff);
  uint32_t s = 0;
#pragma unroll
  for (int k = 0; k < 4; ++k) { uint4 a = p[k]; s += a.x + a.y + a.z + a.w; }
  if (zbuf) {
    uint4* q = reinterpret_cast<uint4*>(zbuf + boff);
    uint4 z = {0u, 0u, 0u, 0u};
#pragma unroll
    for (int k = 0; k < 4; ++k) q[k] = z;
  }
  lds[t] = s;
  __syncthreads();
  for (int off = 128; off > 0; off >>= 1) {
    if (t < off) lds[t] += lds[t + off];
    __syncthreads();
  }
  if (t == 0) partials[blockIdx.y * 64 + blockIdx.x] = lds[0];
}

__global__ __launch_bounds__(256) void scan_b_k(uint32_t* __restrict__ partials) {
  __shared__ uint32_t lds[256];
  const int t = threadIdx.x;
  uint32_t* p = partials + blockIdx.y * 64;
  uint32_t v = (t < SNB) ? p[t] : 0u;
  uint32_t ex = block_excl_scan_256(v, lds);
  if (t < SNB) p[t] = ex;
}

__global__ __launch_bounds__(256) void scan_c_k(uint32_t* __restrict__ cnt,
                                                const uint32_t* __restrict__ partials) {
  __shared__ uint32_t lds[256];
  const int t = threadIdx.x;
  uint32_t* c = cnt + (size_t)blockIdx.y * HL +
                (size_t)blockIdx.x * SCHUNK + (size_t)t * 16;
  uint4* p = reinterpret_cast<uint4*>(c);
  uint4 a[4];
  uint32_t s = 0;
#pragma unroll
  for (int k = 0; k < 4; ++k) {
    a[k] = p[k];
    s += a[k].x + a[k].y + a[k].z + a[k].w;
  }
  uint32_t ex = block_excl_scan_256(s, lds);
  uint32_t run = partials[blockIdx.y * 64 + blockIdx.x] + ex;
#pragma unroll
  for (int k = 0; k < 4; ++k) {
    uint4 o;
    o.x = run; run += a[k].x;
    o.y = run; run += a[k].y;
    o.z = run; run += a[k].z;
    o.w = run; run += a[k].w;
    p[k] = o;
  }
}

// ---------- dual packed-u16 exclusive scan over 256 threads ----------
__device__ __forceinline__ void scan_pack2(uint32_t v0, uint32_t v1, uint32_t* s,
                                           uint32_t& ex0, uint32_t& ex1,
                                           uint32_t& tot0, uint32_t& tot1) {
  const int lane = threadIdx.x & 63, w = threadIdx.x >> 6;
  uint32_t a = v0, b = v1;
#pragma unroll
  for (int o = 1; o < 64; o <<= 1) {
    uint32_t na = __shfl_up(a, (unsigned)o, 64);
    uint32_t nb = __shfl_up(b, (unsigned)o, 64);
    if (lane >= o) { a += na; b += nb; }
  }
  if (lane == 63) { s[w] = a; s[4 + w] = b; }
  __syncthreads();   // NOTE: also the read/write fence for the in-place split
  if (threadIdx.x == 0) {
    uint32_t r0 = 0, r1 = 0;
#pragma unroll
    for (int i = 0; i < 4; ++i) {
      uint32_t q0 = s[i], q1 = s[4 + i];
      s[i] = r0; s[4 + i] = r1;
      r0 += q0; r1 += q1;
    }
    s[8] = r0; s[9] = r1;
  }
  __syncthreads();
  ex0 = a - v0 + s[w];
  ex1 = b - v1 + s[4 + w];
  tot0 = s[8]; tot1 = s[9];
  __syncthreads();  // protect scratch before next-round reuse
}

// ---------- stable partition pass (templated digit P, output MODE) ----------
// MODE 0: write pairs to dst; MODE 1: tsorted[dest]=val; MODE 2: out[idx]=tsorted[dest]
// ACC 1: accumulate next pass's histogram (digit P+1, binned by dest block)
// into HbkN in [bin][blk] scan order via fire-and-forget global atomics.
template <int P, int MODE, int ACC>
__global__ __launch_bounds__(256) void part_k(const uint64_t* __restrict__ src,
                                              uint64_t* __restrict__ dst,
                                              const uint32_t* __restrict__ Hbk,
                                              uint32_t* __restrict__ HbkN,
                                              float* __restrict__ tsorted,
                                              float* __restrict__ out,
                                              int segbase, int slbase) {
  __shared__ uint64_t buf[SBUF];       // single tile buffer (in-place split)
  __shared__ uint32_t ldsStart[RADIX];
  __shared__ uint32_t ldsBase[RADIX];
  __shared__ uint32_t scanS[12];
  const int t = threadIdx.x;
  const int blk = blockIdx.x;
  const int sl = slbase + blockIdx.y;
  const int seg = segbase + sl;
  const uint64_t* ps = src + (size_t)sl * SEG_N + (size_t)blk * TILE;

  // hoisted: per-digit global base (uncoalesced gather; latency hides under
  // the sort rounds — first consumer is the emit loop at the end)
  ldsBase[t] = Hbk[(size_t)sl * HL + (size_t)t * NBLK + blk];

  // stage tile into LDS (coalesced), padded layout
#pragma unroll
  for (int r = 0; r < 16; ++r) buf[SIDX(r * 256 + t)] = ps[r * 256 + t];
  __syncthreads();

  // 4 stable 2-bit split rounds (LSB-first within the byte), IN PLACE:
  // every thread reads its 16 elements into registers BEFORE the first
  // barrier inside scan_pack2; all scatter writes happen AFTER it.
  uint64_t e[16];
#pragma unroll
  for (int rnd = 0; rnd < 4; ++rnd) {
#pragma unroll
    for (int j = 0; j < 16; ++j) e[j] = buf[SIDX(t * 16 + j)];
    uint32_t cnt[4] = {0u, 0u, 0u, 0u};
#pragma unroll
    for (int j = 0; j < 16; ++j) {
      uint32_t d2 = (uint32_t)(e[j] >> (32 + 8 * P + 2 * rnd)) & 3u;
      cnt[d2]++;
    }
    uint32_t p0 = cnt[0] | (cnt[1] << 16);
    uint32_t p1 = cnt[2] | (cnt[3] << 16);
    uint32_t ex0, ex1, tot0, tot1;
    scan_pack2(p0, p1, scanS, ex0, ex1, tot0, tot1);
    uint32_t t0 = tot0 & 0xffffu, t1 = tot0 >> 16, t2 = tot1 & 0xffffu;
    uint32_t pos[4];
    pos[0] = (ex0 & 0xffffu);
    pos[1] = t0 + (ex0 >> 16);
    pos[2] = t0 + t1 + (ex1 & 0xffffu);
    pos[3] = t0 + t1 + t2 + (ex1 >> 16);
#pragma unroll
    for (int j = 0; j < 16; ++j) {
      uint32_t d2 = (uint32_t)(e[j] >> (32 + 8 * P + 2 * rnd)) & 3u;
      buf[SIDX(pos[d2]++)] = e[j];
    }
    __syncthreads();
  }
  // buf: tile stably sorted by digit P

  // per-digit local starts via sorted-run boundary detection (replaces the
  // LDS-atomic histogram + scan: start-of-run == exclusive prefix of counts).
  // Only digits present in the tile get a start — those are the only ones read.
  const uint8_t* b8 = reinterpret_cast<const uint8_t*>(buf);
#pragma unroll
  for (int r = 0; r < 16; ++r) {
    uint32_t s = (uint32_t)(r * 256 + t);
    e[r] = buf[SIDX(s)];
    uint32_t d = (uint32_t)(e[r] >> (32 + 8 * P)) & 255u;
    uint32_t dp = (s == 0) ? 0x100u
                           : (uint32_t)b8[(size_t)SIDX(s - 1) * 8 + 4 + P];
    if (d != dp) ldsStart[d] = s;
  }
  __syncthreads();

  // emit in sorted-tile order: digit runs -> contiguous global ranges.
  // ACC: also count this element for the NEXT pass's histogram at its
  // destination block (exact, order-independent => deterministic).
#pragma unroll
  for (int r = 0; r < 16; ++r) {
    uint32_t s = (uint32_t)(r * 256 + t);
    uint64_t el = e[r];
    uint32_t key = (uint32_t)(el >> 32);
    uint32_t d = (key >> (8 * P)) & 255u;
    uint32_t dest = ldsBase[d] + s - ldsStart[d];
    if (MODE == 0) {
      dst[(size_t)sl * SEG_N + dest] = el;
    } else if (MODE == 1) {
      tsorted[dest] = finv(key);
    } else {
      out[(size_t)(seg - 1) * SEG_N + (uint32_t)el] = tsorted[dest];
    }
    if (ACC) {
      uint32_t nd = (key >> (8 * (P + 1 < 4 ? P + 1 : 0))) & 255u;
      atomicAdd(&HbkN[(size_t)sl * HL + (size_t)nd * NBLK + (dest >> 12)], 1u);
    }
  }
}

// ---------------------------------------------------------------------------
extern "C" void kernel_launch(void* const* d_in, const int* in_sizes, int n_in,
                              void* d_out, int out_size, void* d_ws, size_t ws_size,
                              hipStream_t stream) {
  const float* x = (const float*)d_in[0];
  const float* tmpl = (const float*)d_in[1];
  float* out = (float*)d_out;

  auto need = [](int nb) -> size_t {
    return (size_t)nb * ((size_t)SEG_N * 16 + (size_t)HL * 8 + 256) +
           (size_t)SEG_N * 4 + 8192;
  };
  const int nb = (ws_size >= need(9)) ? 9 : (ws_size >= need(3)) ? 3 : 1;

  uint8_t* w = (uint8_t*)d_ws;
  size_t off = 0;
  auto carve = [&](size_t bytes) -> void* {
    void* p = w + off;
    off = (off + bytes + 255) & ~(size_t)255;
    return p;
  };
  uint64_t* pairsA = (uint64_t*)carve((size_t)nb * SEG_N * 8);
  uint64_t* pairsB = (uint64_t*)carve((size_t)nb * SEG_N * 8);
  uint32_t* Hkb = (uint32_t*)carve((size_t)nb * HL * 4);
  uint32_t* Hbk = (uint32_t*)carve((size_t)nb * HL * 4);
  uint32_t* partials = (uint32_t*)carve((size_t)nb * 64 * 4);
  float* tsorted = (float*)carve((size_t)SEG_N * 4);

  for (int g = 0; g < NSEG; g += nb) {
    const dim3 gi(NBLK, nb);
    const dim3 gt(40, nb);
    const dim3 gs(SNB, nb);
    const dim3 g1(1, nb);

    // scan counts in `cur` into offsets; zero `zb` (next accumulation target)
    auto scan_h = [&](uint32_t* cur, uint32_t* zb) {
      scan_a_k<<<gs, 256, 0, stream>>>(cur, partials, zb);
      scan_b_k<<<g1, 256, 0, stream>>>(partials);
      scan_c_k<<<gs, 256, 0, stream>>>(cur, partials);
    };

    // pass 0 (digit-0 hist fused into init; [blk][bin] -> transpose once)
    init_k<<<gi, 256, 0, stream>>>(x, tmpl, g, pairsA, Hkb);
    transp_k<<<gt, 256, 0, stream>>>(Hkb, Hbk);
    scan_h(Hbk, Hkb);  // Hkb dead after transpose -> becomes pass-1 acc target
    part_k<0, 0, 1><<<gi, 256, 0, stream>>>(pairsA, pairsB, Hbk, Hkb,
                                            tsorted, out, g, 0);
    // pass 1 (counts already in Hkb, accumulated by part<0>)
    scan_h(Hkb, Hbk);
    part_k<1, 0, 1><<<gi, 256, 0, stream>>>(pairsB, pairsA, Hkb, Hbk,
                                            tsorted, out, g, 0);
    // pass 2
    scan_h(Hbk, Hkb);
    part_k<2, 0, 1><<<gi, 256, 0, stream>>>(pairsA, pairsB, Hbk, Hkb,
                                            tsorted, out, g, 0);
    // pass 3 (fused epilogue; no further histogram)
    scan_h(Hkb, nullptr);
    if (g == 0) {
      part_k<3, 1, 0><<<dim3(NBLK, 1), 256, 0, stream>>>(pairsB, pairsA, Hkb,
                                                         nullptr, tsorted, out,
                                                         g, 0);
      if (nb > 1)
        part_k<3, 2, 0><<<dim3(NBLK, nb - 1), 256, 0, stream>>>(
            pairsB, pairsA, Hkb, nullptr, tsorted, out, g, 1);
    } else {
      part_k<3, 2, 0><<<dim3(NBLK, nb), 256, 0, stream>>>(
          pairsB, pairsA, Hkb, nullptr, tsorted, out, g, 0);
    }
  }
}

// Round 3
// 1262.595 us; speedup vs baseline: 3.5304x; 3.5304x over previous
//
#include <hip/hip_runtime.h>
#include <stdint.h>

// HistMatching via stable LSD radix sort (4 x 8-bit passes) of (key32,idx32)
// u64 pairs per segment, ONESWEEP-style:
//   init_k  : build pairs + per-block u16 histograms of ALL 4 digits (one read)
//   hscan_a/b: reduce + exclusive-scan -> per-segment per-pass 256-bin bases
//   sort_k  : per pass, tile hist -> publish aggregate -> 4x2-bit in-place
//             split rounds -> decoupled lookback (ticketed, batched-8) -> emit.
// Final pass fuses the epilogue: template -> tsorted[dest]=val; samples ->
// out[idx]=tsorted[dest].
//
// R1: single-LDS-buffer in-place split (4 blocks/CU), run-boundary starts.
// R2 (REVERTED): per-element global atomics for fused hist = +575us/pass.
// R3: onesweep. Tickets pin tile order (no dispatch-order assumption, no
//     deadlock); desc = flag[31:30]|value[29:0] in ONE u32 -> relaxed
//     agent-scope atomics suffice. hist_k/transp_k/scan_* all deleted.

#define SEG_N 2621440            // 128*160*128
#define NSEG 9                   // template + 8 samples
#define TILE 4096
#define NBLK (SEG_N / TILE)      // 640 blocks per segment
#define RADIX 256
#define SBUF (TILE + (TILE >> 4))  // 4352 u64, padded 1-per-16
#define DESC_SL (NBLK * RADIX)   // 163840 desc words per segment-slot

// monotone f32 -> u32 (order-preserving)
__device__ __forceinline__ uint32_t fkey(float f) {
  uint32_t b = __float_as_uint(f);
  return b ^ ((b & 0x80000000u) ? 0xFFFFFFFFu : 0x80000000u);
}
__device__ __forceinline__ float finv(uint32_t u) {
  uint32_t b = u ^ ((u & 0x80000000u) ? 0x80000000u : 0xFFFFFFFFu);
  return __uint_as_float(b);
}
__device__ __forceinline__ uint32_t SIDX(uint32_t i) { return i + (i >> 4); }

__device__ __forceinline__ uint32_t wave_incl_scan(uint32_t v) {
  const int lane = threadIdx.x & 63;
#pragma unroll
  for (int o = 1; o < 64; o <<= 1) {
    uint32_t n = __shfl_up(v, (unsigned)o, 64);
    if (lane >= o) v += n;
  }
  return v;
}

// ---------- init: pairs in index order + per-block 4-digit u16 hists ----------
__global__ __launch_bounds__(256) void init_k(const float* __restrict__ x,
                                              const float* __restrict__ tmpl,
                                              int segbase,
                                              uint64_t* __restrict__ pairsA,
                                              uint16_t* __restrict__ Hblk) {
  __shared__ uint32_t hw[4 * 4 * 256];  // [wave][pass][bin]
  const int t = threadIdx.x;
  const int blk = blockIdx.x;
  const int sl = blockIdx.y;
  const int seg = segbase + sl;
  const float* src = (seg == 0) ? tmpl : (x + (size_t)(seg - 1) * SEG_N);
  uint64_t* pa = pairsA + (size_t)sl * SEG_N;
#pragma unroll
  for (int i = 0; i < 16; ++i) hw[t + 256 * i] = 0;
  __syncthreads();
  const int w = t >> 6;
  const uint32_t base = blk * TILE;
  const float4* s4 = reinterpret_cast<const float4*>(src + base);
#pragma unroll
  for (int r = 0; r < 4; ++r) {
    float4 v = s4[r * 256 + t];
    uint32_t i0 = base + (uint32_t)(r * 256 + t) * 4u;
    float f[4] = {v.x, v.y, v.z, v.w};
#pragma unroll
    for (int c = 0; c < 4; ++c) {
      uint32_t k = fkey(f[c]);
      atomicAdd(&hw[(w * 4 + 0) * 256 + (k & 255u)], 1u);
      atomicAdd(&hw[(w * 4 + 1) * 256 + ((k >> 8) & 255u)], 1u);
      atomicAdd(&hw[(w * 4 + 2) * 256 + ((k >> 16) & 255u)], 1u);
      atomicAdd(&hw[(w * 4 + 3) * 256 + (k >> 24)], 1u);
      pa[i0 + c] = ((uint64_t)k << 32) | (uint64_t)(i0 + c);
    }
  }
  __syncthreads();
  uint16_t* hrow = Hblk + (size_t)(sl * NBLK + blk) * 1024;
#pragma unroll
  for (int p = 0; p < 4; ++p) {
    uint32_t s = hw[(0 * 4 + p) * 256 + t] + hw[(1 * 4 + p) * 256 + t] +
                 hw[(2 * 4 + p) * 256 + t] + hw[(3 * 4 + p) * 256 + t];
    hrow[p * 256 + t] = (uint16_t)s;
  }
}

// ---------- reduce per-block hists: stage 1 (16 blocks per partial) ----------
__global__ __launch_bounds__(256) void hscan_a_k(const uint16_t* __restrict__ Hblk,
                                                 uint32_t* __restrict__ partial) {
  const int t = threadIdx.x;
  const int c = blockIdx.x;   // 0..39
  const int sl = blockIdx.y;
  uint32_t s0 = 0, s1 = 0, s2 = 0, s3 = 0;
#pragma unroll
  for (int i = 0; i < 16; ++i) {
    const uint16_t* row =
        Hblk + (size_t)(sl * NBLK + c * 16 + i) * 1024 + t * 4;
    uint2 v = *reinterpret_cast<const uint2*>(row);
    s0 += v.x & 0xffffu; s1 += v.x >> 16;
    s2 += v.y & 0xffffu; s3 += v.y >> 16;
  }
  uint4 o = {s0, s1, s2, s3};
  *reinterpret_cast<uint4*>(partial + ((size_t)sl * 40 + c) * 1024 + t * 4) = o;
}

// ---------- stage 2: final reduce + per-pass exclusive scan over bins ----------
// wave w handles pass p=w (cols t*4..t*4+3 == p*256+bin), 4 bins/lane.
__global__ __launch_bounds__(256) void hscan_b_k(const uint32_t* __restrict__ partial,
                                                 uint32_t* __restrict__ segBases) {
  const int t = threadIdx.x;
  const int sl = blockIdx.x;
  uint32_t s0 = 0, s1 = 0, s2 = 0, s3 = 0;
#pragma unroll 8
  for (int c = 0; c < 40; ++c) {
    uint4 v = *reinterpret_cast<const uint4*>(
        partial + ((size_t)sl * 40 + c) * 1024 + t * 4);
    s0 += v.x; s1 += v.y; s2 += v.z; s3 += v.w;
  }
  uint32_t local = s0 + s1 + s2 + s3;
  uint32_t incl = wave_incl_scan(local);
  uint32_t ex = incl - local;
  uint4 o;
  o.x = ex; o.y = ex + s0; o.z = ex + s0 + s1; o.w = ex + s0 + s1 + s2;
  *reinterpret_cast<uint4*>(segBases + (size_t)sl * 1024 + t * 4) = o;
}

// ---------- dual packed-u16 exclusive scan over 256 threads ----------
__device__ __forceinline__ void scan_pack2(uint32_t v0, uint32_t v1, uint32_t* s,
                                           uint32_t& ex0, uint32_t& ex1,
                                           uint32_t& tot0, uint32_t& tot1) {
  const int lane = threadIdx.x & 63, w = threadIdx.x >> 6;
  uint32_t a = v0, b = v1;
#pragma unroll
  for (int o = 1; o < 64; o <<= 1) {
    uint32_t na = __shfl_up(a, (unsigned)o, 64);
    uint32_t nb = __shfl_up(b, (unsigned)o, 64);
    if (lane >= o) { a += na; b += nb; }
  }
  if (lane == 63) { s[w] = a; s[4 + w] = b; }
  __syncthreads();   // also the read/write fence for the in-place split
  if (threadIdx.x == 0) {
    uint32_t r0 = 0, r1 = 0;
#pragma unroll
    for (int i = 0; i < 4; ++i) {
      uint32_t q0 = s[i], q1 = s[4 + i];
      s[i] = r0; s[4 + i] = r1;
      r0 += q0; r1 += q1;
    }
    s[8] = r0; s[9] = r1;
  }
  __syncthreads();
  ex0 = a - v0 + s[w];
  ex1 = b - v1 + s[4 + w];
  tot0 = s[8]; tot1 = s[9];
  __syncthreads();  // protect scratch before next-round reuse
}

// ---------- onesweep sort pass (digit P, output MODE) ----------
// MODE 0: pairs->dst; MODE 1: tsorted[dest]=val; MODE 2: out[idx]=tsorted[dest]
template <int P, int MODE>
__global__ __launch_bounds__(256) void sort_k(
    const uint64_t* __restrict__ src, uint64_t* __restrict__ dst,
    uint32_t* __restrict__ descCur, uint32_t* __restrict__ descNext,
    const uint32_t* __restrict__ segBases, uint32_t* __restrict__ tickets,
    float* __restrict__ tsorted, float* __restrict__ out,
    int segbase, int slbase) {
  __shared__ uint64_t buf[SBUF];
  __shared__ uint32_t aux[1024];     // histW[4][256], later start[256]+base[256]
  __shared__ uint32_t scanS[12];
  __shared__ uint32_t myblkS;
  const int t = threadIdx.x;
  const int sl = slbase + blockIdx.y;
  const int seg = segbase + sl;
  if (t == 0) myblkS = atomicAdd(&tickets[P * 16 + sl], 1u);
  aux[t] = 0; aux[t + 256] = 0; aux[t + 512] = 0; aux[t + 768] = 0;
  __syncthreads();
  const uint32_t myblk = myblkS;

  // zero next pass's desc row + ticket (dead; visible at kernel boundary)
  descNext[(size_t)sl * DESC_SL + (size_t)myblk * RADIX + t] = 0;
  if (t == 0) tickets[((P + 1) & 3) * 16 + sl] = 0;

  const uint64_t* ps = src + (size_t)sl * SEG_N + (size_t)myblk * TILE;
#pragma unroll
  for (int r = 0; r < 16; ++r) buf[SIDX(r * 256 + t)] = ps[r * 256 + t];
  __syncthreads();

  // per-tile 256-bin hist (per-wave replicated) + EARLY aggregate publish
  const int w = t >> 6;
  uint64_t e[16];
#pragma unroll
  for (int j = 0; j < 16; ++j) e[j] = buf[SIDX(t * 16 + j)];
#pragma unroll
  for (int j = 0; j < 16; ++j)
    atomicAdd(&aux[w * 256 + ((uint32_t)(e[j] >> (32 + 8 * P)) & 255u)], 1u);
  __syncthreads();
  const uint32_t cnt = aux[t] + aux[t + 256] + aux[t + 512] + aux[t + 768];
  uint32_t* drow = descCur + (size_t)sl * DESC_SL + (size_t)myblk * RADIX;
  __hip_atomic_store(&drow[t], cnt | ((myblk == 0 ? 2u : 1u) << 30),
                     __ATOMIC_RELAXED, __HIP_MEMORY_SCOPE_AGENT);

  // 4 stable 2-bit in-place split rounds (reads->regs before the first
  // barrier in scan_pack2; scatters after it => race-free, R1-verified)
#pragma unroll
  for (int rnd = 0; rnd < 4; ++rnd) {
    if (rnd > 0) {
#pragma unroll
      for (int j = 0; j < 16; ++j) e[j] = buf[SIDX(t * 16 + j)];
    }
    uint32_t c4[4] = {0u, 0u, 0u, 0u};
#pragma unroll
    for (int j = 0; j < 16; ++j) {
      uint32_t d2 = (uint32_t)(e[j] >> (32 + 8 * P + 2 * rnd)) & 3u;
      c4[d2]++;
    }
    uint32_t p0 = c4[0] | (c4[1] << 16);
    uint32_t p1 = c4[2] | (c4[3] << 16);
    uint32_t ex0, ex1, tot0, tot1;
    scan_pack2(p0, p1, scanS, ex0, ex1, tot0, tot1);
    uint32_t t0 = tot0 & 0xffffu, t1 = tot0 >> 16, t2 = tot1 & 0xffffu;
    uint32_t pos[4];
    pos[0] = (ex0 & 0xffffu);
    pos[1] = t0 + (ex0 >> 16);
    pos[2] = t0 + t1 + (ex1 & 0xffffu);
    pos[3] = t0 + t1 + t2 + (ex1 >> 16);
#pragma unroll
    for (int j = 0; j < 16; ++j) {
      uint32_t d2 = (uint32_t)(e[j] >> (32 + 8 * P + 2 * rnd)) & 3u;
      buf[SIDX(pos[d2]++)] = e[j];
    }
    __syncthreads();
  }
  // buf: tile stably sorted by digit P

  // per-digit local starts via sorted-run boundary detection
  uint32_t* ldsStart = aux;
  uint32_t* ldsBase = aux + 256;
  const uint8_t* b8 = reinterpret_cast<const uint8_t*>(buf);
#pragma unroll
  for (int r = 0; r < 16; ++r) {
    uint32_t s = (uint32_t)(r * 256 + t);
    e[r] = buf[SIDX(s)];
    uint32_t d = (uint32_t)(e[r] >> (32 + 8 * P)) & 255u;
    uint32_t dp = (s == 0) ? 0x100u
                           : (uint32_t)b8[(size_t)SIDX(s - 1) * 8 + 4 + P];
    if (d != dp) ldsStart[d] = s;
  }

  // decoupled lookback (batched-8 speculative loads, flag|value in one word)
  uint32_t acc = 0;
  if (myblk > 0) {
    uint32_t* dcol = descCur + (size_t)sl * DESC_SL + t;
    int b = (int)myblk - 1;
    for (;;) {
      uint32_t dv[8];
      const int n = (b >= 7) ? 8 : (b + 1);
#pragma unroll
      for (int i = 0; i < 8; ++i)
        if (i < n)
          dv[i] = __hip_atomic_load(&dcol[(size_t)(b - i) * RADIX],
                                    __ATOMIC_RELAXED, __HIP_MEMORY_SCOPE_AGENT);
      bool done = false;
      for (int i = 0; i < n; ++i) {
        uint32_t v = dv[i];
        while ((v >> 30) == 0u)
          v = __hip_atomic_load(&dcol[(size_t)(b - i) * RADIX],
                                __ATOMIC_RELAXED, __HIP_MEMORY_SCOPE_AGENT);
        acc += v & 0x3FFFFFFFu;
        if ((v >> 30) == 2u) { done = true; break; }
      }
      if (done) break;
      b -= n;
      if (b < 0) break;  // unreachable: block 0 publishes PREFIX
    }
    __hip_atomic_store(&drow[t], (acc + cnt) | (2u << 30),
                       __ATOMIC_RELAXED, __HIP_MEMORY_SCOPE_AGENT);
  }
  ldsBase[t] = segBases[(size_t)(sl * 4 + P) * 256 + t] + acc;
  __syncthreads();

  // emit in sorted-tile order: digit runs -> contiguous global ranges
#pragma unroll
  for (int r = 0; r < 16; ++r) {
    uint32_t s = (uint32_t)(r * 256 + t);
    uint64_t el = e[r];
    uint32_t key = (uint32_t)(el >> 32);
    uint32_t d = (key >> (8 * P)) & 255u;
    uint32_t dest = ldsBase[d] + s - ldsStart[d];
    if (MODE == 0) {
      dst[(size_t)sl * SEG_N + dest] = el;
    } else if (MODE == 1) {
      tsorted[dest] = finv(key);
    } else {
      out[(size_t)(seg - 1) * SEG_N + (uint32_t)el] = tsorted[dest];
    }
  }
}

// ---------------------------------------------------------------------------
extern "C" void kernel_launch(void* const* d_in, const int* in_sizes, int n_in,
                              void* d_out, int out_size, void* d_ws, size_t ws_size,
                              hipStream_t stream) {
  const float* x = (const float*)d_in[0];
  const float* tmpl = (const float*)d_in[1];
  float* out = (float*)d_out;

  auto need = [](int nbv) -> size_t {
    return (size_t)nbv * ((size_t)SEG_N * 16 + (size_t)NBLK * 1024 * 2 + 4096) +
           (size_t)SEG_N * 4 + 16384;
  };
  const int nb = (ws_size >= need(9)) ? 9 : (ws_size >= need(3)) ? 3 : 1;

  uint8_t* w = (uint8_t*)d_ws;
  size_t off = 0;
  auto carve = [&](size_t bytes) -> void* {
    void* p = w + off;
    off = (off + bytes + 255) & ~(size_t)255;
    return p;
  };
  uint64_t* pairsA = (uint64_t*)carve((size_t)nb * SEG_N * 8);
  uint64_t* pairsB = (uint64_t*)carve((size_t)nb * SEG_N * 8);
  // desc region; Hblk (u16 per-block hists) aliases it (disjoint lifetime)
  uint32_t* descA = (uint32_t*)carve((size_t)nb * DESC_SL * 4 * 2);
  uint32_t* descB = descA + (size_t)nb * DESC_SL;
  uint16_t* Hblk = (uint16_t*)descA;
  uint32_t* segBases = (uint32_t*)carve((size_t)nb * 1024 * 4);
  uint32_t* tickets = (uint32_t*)carve(64 * 4);
  float* tsorted = (float*)carve((size_t)SEG_N * 4);
  // hscan partial aliases pairsB (dead until sort pass 0 writes it)
  uint32_t* partial = (uint32_t*)pairsB;

  hipMemsetAsync(tickets, 0, 64 * 4, stream);

  for (int g = 0; g < NSEG; g += nb) {
    const dim3 gi(NBLK, nb);

    init_k<<<gi, 256, 0, stream>>>(x, tmpl, g, pairsA, Hblk);
    hscan_a_k<<<dim3(40, nb), 256, 0, stream>>>(Hblk, partial);
    hscan_b_k<<<dim3(nb), 256, 0, stream>>>(partial, segBases);
    hipMemsetAsync(descA, 0, (size_t)nb * DESC_SL * 4 * 2, stream);

    sort_k<0, 0><<<gi, 256, 0, stream>>>(pairsA, pairsB, descA, descB,
                                         segBases, tickets, tsorted, out, g, 0);
    sort_k<1, 0><<<gi, 256, 0, stream>>>(pairsB, pairsA, descB, descA,
                                         segBases, tickets, tsorted, out, g, 0);
    sort_k<2, 0><<<gi, 256, 0, stream>>>(pairsA, pairsB, descA, descB,
                                         segBases, tickets, tsorted, out, g, 0);
    if (g == 0) {
      sort_k<3, 1><<<dim3(NBLK, 1), 256, 0, stream>>>(
          pairsB, pairsA, descB, descA, segBases, tickets, tsorted, out, g, 0);
      if (nb > 1)
        sort_k<3, 2><<<dim3(NBLK, nb - 1), 256, 0, stream>>>(
            pairsB, pairsA, descB, descA, segBases, tickets, tsorted, out, g, 1);
    } else {
      sort_k<3, 2><<<dim3(NBLK, nb), 256, 0, stream>>>(
          pairsB, pairsA, descB, descA, segBases, tickets, tsorted, out, g, 0);
    }
  }
}

// Round 4
// 1171.155 us; speedup vs baseline: 3.8061x; 1.0781x over previous
//
#include <hip/hip_runtime.h>
#include <stdint.h>

// HistMatching via stable LSD radix sort (4 x 8-bit passes), SoA layout:
// key32 and idx32 in separate arrays. Stability via per-(bin,block) histogram
// matrix + exclusive scan. Final pass fuses the epilogue: template ->
// tsorted[dest]=val; samples -> out[idx]=tsorted[dest].
//
// R1: single-LDS-buffer in-place split, run-boundary starts, hoisted bases.
// R2 (REVERTED): per-element global atomics for fused hist (+575us/pass).
// R3 (REVERTED): onesweep lookback — LDS-atomic tile hists on skewed digits
//     cost more than the deleted prepass kernels.
// R4: SoA. hist_k reads keys only (94MB vs 189MB). part_k LDS = u32 keys +
//     u16 local pos = 28.2KB -> 5 blocks/CU (was 4). Per-wave replicated
//     hists in init/hist kill hot-bin inter-wave atomic contention. Template
//     segment skips idx entirely (epilogue never uses it).

#define SEG_N 2621440            // 128*160*128
#define NSEG 9                   // template + 8 samples
#define TILE 4096
#define NBLK (SEG_N / TILE)      // 640 blocks per segment
#define RADIX 256
#define HL (RADIX * NBLK)        // 163840 histogram-matrix entries per seg
#define SCHUNK 4096
#define SNB (HL / SCHUNK)        // 40 scan blocks per seg
#define SBUFE (TILE + (TILE >> 4))  // 4352 elems, padded 1-per-16

// monotone f32 -> u32 (order-preserving)
__device__ __forceinline__ uint32_t fkey(float f) {
  uint32_t b = __float_as_uint(f);
  return b ^ ((b & 0x80000000u) ? 0xFFFFFFFFu : 0x80000000u);
}
__device__ __forceinline__ float finv(uint32_t u) {
  uint32_t b = u ^ ((u & 0x80000000u) ? 0x80000000u : 0xFFFFFFFFu);
  return __uint_as_float(b);
}
__device__ __forceinline__ uint32_t SIDX(uint32_t i) { return i + (i >> 4); }

// ---------- init: build keyA (+ idxA for samples) + digit-0 histogram ----------
__global__ __launch_bounds__(256) void init_k(const float* __restrict__ x,
                                              const float* __restrict__ tmpl,
                                              int segbase,
                                              uint32_t* __restrict__ keyA,
                                              uint32_t* __restrict__ idxA,
                                              uint32_t* __restrict__ Hkb) {
  __shared__ uint32_t hw[4 * RADIX];   // per-wave replicated
  const int t = threadIdx.x;
  const int blk = blockIdx.x;
  const int sl = blockIdx.y;
  const int seg = segbase + sl;
  const float* src = (seg == 0) ? tmpl : (x + (size_t)(seg - 1) * SEG_N);
  uint32_t* ka = keyA + (size_t)sl * SEG_N;
  uint32_t* ia = idxA + (size_t)sl * SEG_N;
  hw[t] = 0; hw[t + 256] = 0; hw[t + 512] = 0; hw[t + 768] = 0;
  __syncthreads();
  const int w = t >> 6;
  const uint32_t base = blk * TILE;
  const float4* s4 = reinterpret_cast<const float4*>(src + base);
#pragma unroll
  for (int r = 0; r < 4; ++r) {
    float4 v = s4[r * 256 + t];
    uint32_t i0 = base + (uint32_t)(r * 256 + t) * 4u;
    uint4 kv;
    kv.x = fkey(v.x); kv.y = fkey(v.y); kv.z = fkey(v.z); kv.w = fkey(v.w);
    atomicAdd(&hw[w * 256 + (kv.x & 255u)], 1u);
    atomicAdd(&hw[w * 256 + (kv.y & 255u)], 1u);
    atomicAdd(&hw[w * 256 + (kv.z & 255u)], 1u);
    atomicAdd(&hw[w * 256 + (kv.w & 255u)], 1u);
    *reinterpret_cast<uint4*>(ka + i0) = kv;
    if (seg != 0) {
      uint4 iv = {i0, i0 + 1u, i0 + 2u, i0 + 3u};
      *reinterpret_cast<uint4*>(ia + i0) = iv;
    }
  }
  __syncthreads();
  Hkb[(size_t)sl * HL + (size_t)blk * RADIX + t] =
      hw[t] + hw[t + 256] + hw[t + 512] + hw[t + 768];   // [blk][bin]
}

// ---------- histogram of digit p over keys only (94MB read, not 189) ----------
__global__ __launch_bounds__(256) void hist_k(const uint32_t* __restrict__ keys,
                                              uint32_t* __restrict__ Hkb, int p) {
  __shared__ uint32_t hw[4 * RADIX];   // per-wave replicated
  const int t = threadIdx.x;
  const int blk = blockIdx.x;
  const int sl = blockIdx.y;
  const uint32_t* kc = keys + (size_t)sl * SEG_N + (size_t)blk * TILE;
  hw[t] = 0; hw[t + 256] = 0; hw[t + 512] = 0; hw[t + 768] = 0;
  __syncthreads();
  const int w = t >> 6;
  const int sh = 8 * p;
  const uint4* k4 = reinterpret_cast<const uint4*>(kc);
#pragma unroll
  for (int r = 0; r < 4; ++r) {
    uint4 v = k4[r * 256 + t];
    atomicAdd(&hw[w * 256 + ((v.x >> sh) & 255u)], 1u);
    atomicAdd(&hw[w * 256 + ((v.y >> sh) & 255u)], 1u);
    atomicAdd(&hw[w * 256 + ((v.z >> sh) & 255u)], 1u);
    atomicAdd(&hw[w * 256 + ((v.w >> sh) & 255u)], 1u);
  }
  __syncthreads();
  Hkb[(size_t)sl * HL + (size_t)blk * RADIX + t] =
      hw[t] + hw[t + 256] + hw[t + 512] + hw[t + 768];
}

// ---------- transpose [blk][bin] -> [bin][blk] (scan-order) ----------
__global__ __launch_bounds__(256) void transp_k(const uint32_t* __restrict__ Hkb,
                                                uint32_t* __restrict__ Hbk) {
  __shared__ uint32_t tile[64][65];
  const int sl = blockIdx.y;
  const uint32_t* src = Hkb + (size_t)sl * HL;
  uint32_t* dst = Hbk + (size_t)sl * HL;
  const int kt = blockIdx.x % (NBLK / 64);  // 10 k-tiles
  const int bt = blockIdx.x / (NBLK / 64);  // 4 b-tiles
  const int tx = threadIdx.x & 63, ty = threadIdx.x >> 6;
#pragma unroll
  for (int r = 0; r < 16; ++r) {
    int k = kt * 64 + ty + r * 4;
    tile[ty + r * 4][tx] = src[(size_t)k * RADIX + bt * 64 + tx];
  }
  __syncthreads();
#pragma unroll
  for (int r = 0; r < 16; ++r) {
    int b = bt * 64 + ty + r * 4;
    dst[(size_t)b * NBLK + kt * 64 + tx] = tile[tx][ty + r * 4];
  }
}

// ---------- 3-level exclusive scan over Hbk (length HL per seg) ----------
__device__ __forceinline__ uint32_t block_excl_scan_256(uint32_t v, uint32_t* lds) {
  const int t = threadIdx.x;
  lds[t] = v;
  __syncthreads();
#pragma unroll
  for (int off = 1; off < 256; off <<= 1) {
    uint32_t a = (t >= off) ? lds[t - off] : 0u;
    __syncthreads();
    lds[t] += a;
    __syncthreads();
  }
  uint32_t ex = (t == 0) ? 0u : lds[t - 1];
  __syncthreads();
  return ex;
}

__global__ __launch_bounds__(256) void scan_a_k(const uint32_t* __restrict__ Hbk,
                                                uint32_t* __restrict__ partials) {
  __shared__ uint32_t lds[256];
  const int t = threadIdx.x;
  const uint32_t* c = Hbk + (size_t)blockIdx.y * HL +
                      (size_t)blockIdx.x * SCHUNK + (size_t)t * 16;
  const uint4* p = reinterpret_cast<const uint4*>(c);
  uint32_t s = 0;
#pragma unroll
  for (int k = 0; k < 4; ++k) { uint4 a = p[k]; s += a.x + a.y + a.z + a.w; }
  lds[t] = s;
  __syncthreads();
  for (int off = 128; off > 0; off >>= 1) {
    if (t < off) lds[t] += lds[t + off];
    __syncthreads();
  }
  if (t == 0) partials[blockIdx.y * 64 + blockIdx.x] = lds[0];
}

__global__ __launch_bounds__(256) void scan_b_k(uint32_t* __restrict__ partials) {
  __shared__ uint32_t lds[256];
  const int t = threadIdx.x;
  uint32_t* p = partials + blockIdx.y * 64;
  uint32_t v = (t < SNB) ? p[t] : 0u;
  uint32_t ex = block_excl_scan_256(v, lds);
  if (t < SNB) p[t] = ex;
}

__global__ __launch_bounds__(256) void scan_c_k(uint32_t* __restrict__ Hbk,
                                                const uint32_t* __restrict__ partials) {
  __shared__ uint32_t lds[256];
  const int t = threadIdx.x;
  uint32_t* c = Hbk + (size_t)blockIdx.y * HL +
                (size_t)blockIdx.x * SCHUNK + (size_t)t * 16;
  uint4* p = reinterpret_cast<uint4*>(c);
  uint4 a[4];
  uint32_t s = 0;
#pragma unroll
  for (int k = 0; k < 4; ++k) {
    a[k] = p[k];
    s += a[k].x + a[k].y + a[k].z + a[k].w;
  }
  uint32_t ex = block_excl_scan_256(s, lds);
  uint32_t run = partials[blockIdx.y * 64 + blockIdx.x] + ex;
#pragma unroll
  for (int k = 0; k < 4; ++k) {
    uint4 o;
    o.x = run; run += a[k].x;
    o.y = run; run += a[k].y;
    o.z = run; run += a[k].z;
    o.w = run; run += a[k].w;
    p[k] = o;
  }
}

// ---------- dual packed-u16 exclusive scan over 256 threads ----------
__device__ __forceinline__ void scan_pack2(uint32_t v0, uint32_t v1, uint32_t* s,
                                           uint32_t& ex0, uint32_t& ex1,
                                           uint32_t& tot0, uint32_t& tot1) {
  const int lane = threadIdx.x & 63, w = threadIdx.x >> 6;
  uint32_t a = v0, b = v1;
#pragma unroll
  for (int o = 1; o < 64; o <<= 1) {
    uint32_t na = __shfl_up(a, (unsigned)o, 64);
    uint32_t nb = __shfl_up(b, (unsigned)o, 64);
    if (lane >= o) { a += na; b += nb; }
  }
  if (lane == 63) { s[w] = a; s[4 + w] = b; }
  __syncthreads();   // also the read/write fence for the in-place split
  if (threadIdx.x == 0) {
    uint32_t r0 = 0, r1 = 0;
#pragma unroll
    for (int i = 0; i < 4; ++i) {
      uint32_t q0 = s[i], q1 = s[4 + i];
      s[i] = r0; s[4 + i] = r1;
      r0 += q0; r1 += q1;
    }
    s[8] = r0; s[9] = r1;
  }
  __syncthreads();
  ex0 = a - v0 + s[w];
  ex1 = b - v1 + s[4 + w];
  tot0 = s[8]; tot1 = s[9];
  __syncthreads();  // protect scratch before next-round reuse
}

// ---------- stable partition pass (templated digit P, output MODE) ----------
// MODE 0: key/idx -> dst arrays; MODE 1: tsorted[dest]=val (no idx);
// MODE 2: out[idx]=tsorted[dest]
template <int P, int MODE>
__global__ __launch_bounds__(256) void part_k(const uint32_t* __restrict__ keyIn,
                                              const uint32_t* __restrict__ idxIn,
                                              uint32_t* __restrict__ keyOut,
                                              uint32_t* __restrict__ idxOut,
                                              const uint32_t* __restrict__ Hbk,
                                              float* __restrict__ tsorted,
                                              float* __restrict__ out,
                                              int segbase, int slbase) {
  __shared__ uint32_t bufK[SBUFE];     // tile keys (in-place split)
  __shared__ uint16_t bufP[SBUFE];     // local source position of each slot
  __shared__ uint32_t ldsStart[RADIX];
  __shared__ uint32_t ldsBase[RADIX];
  __shared__ uint32_t scanS[12];
  const int t = threadIdx.x;
  const int blk = blockIdx.x;
  const int sl = slbase + blockIdx.y;
  const int seg = segbase + sl;
  const bool wantIdx = (seg != 0);     // template never needs its permutation
  const size_t segOff = (size_t)sl * SEG_N;
  const uint32_t blkBase = (uint32_t)blk * TILE;
  const uint32_t* ks = keyIn + segOff + blkBase;

  // hoisted: per-digit global base (uncoalesced gather; latency hides under
  // the sort rounds — first consumer is the emit loop at the end)
  ldsBase[t] = Hbk[(size_t)sl * HL + (size_t)t * NBLK + blk];

  // stage keys into LDS (coalesced); pos[slot] = slot
#pragma unroll
  for (int r = 0; r < 16; ++r) {
    uint32_t s = (uint32_t)(r * 256 + t);
    bufK[SIDX(s)] = ks[s];
    bufP[SIDX(s)] = (uint16_t)s;
  }
  __syncthreads();

  // 4 stable 2-bit split rounds (LSB-first within the byte), IN PLACE:
  // every thread reads its 16 elements into registers BEFORE the first
  // barrier inside scan_pack2; all scatter writes happen AFTER it.
  uint32_t k[16];
  uint16_t pr[16];
#pragma unroll
  for (int rnd = 0; rnd < 4; ++rnd) {
#pragma unroll
    for (int j = 0; j < 16; ++j) {
      k[j] = bufK[SIDX(t * 16 + j)];
      pr[j] = bufP[SIDX(t * 16 + j)];
    }
    uint32_t cnt[4] = {0u, 0u, 0u, 0u};
#pragma unroll
    for (int j = 0; j < 16; ++j) {
      uint32_t d2 = (k[j] >> (8 * P + 2 * rnd)) & 3u;
      cnt[d2]++;
    }
    uint32_t p0 = cnt[0] | (cnt[1] << 16);
    uint32_t p1 = cnt[2] | (cnt[3] << 16);
    uint32_t ex0, ex1, tot0, tot1;
    scan_pack2(p0, p1, scanS, ex0, ex1, tot0, tot1);
    uint32_t t0 = tot0 & 0xffffu, t1 = tot0 >> 16, t2 = tot1 & 0xffffu;
    uint32_t pos[4];
    pos[0] = (ex0 & 0xffffu);
    pos[1] = t0 + (ex0 >> 16);
    pos[2] = t0 + t1 + (ex1 & 0xffffu);
    pos[3] = t0 + t1 + t2 + (ex1 >> 16);
#pragma unroll
    for (int j = 0; j < 16; ++j) {
      uint32_t d2 = (k[j] >> (8 * P + 2 * rnd)) & 3u;
      uint32_t pp = pos[d2]++;
      bufK[SIDX(pp)] = k[j];
      bufP[SIDX(pp)] = pr[j];
    }
    __syncthreads();
  }
  // bufK/bufP: tile stably sorted by digit P

  // per-digit local starts via sorted-run boundary detection
  const uint8_t* b8 = reinterpret_cast<const uint8_t*>(bufK);
#pragma unroll
  for (int r = 0; r < 16; ++r) {
    uint32_t s = (uint32_t)(r * 256 + t);
    k[r] = bufK[SIDX(s)];
    pr[r] = bufP[SIDX(s)];
    uint32_t d = (k[r] >> (8 * P)) & 255u;
    uint32_t dp = (s == 0) ? 0x100u
                           : (uint32_t)b8[(size_t)SIDX(s - 1) * 4 + P];
    if (d != dp) ldsStart[d] = s;
  }
  __syncthreads();

  // emit in sorted-tile order: digit runs -> contiguous global ranges.
  // idx payload fetched once here via a 16KB-window gather (L2-local).
#pragma unroll
  for (int r = 0; r < 16; ++r) {
    uint32_t s = (uint32_t)(r * 256 + t);
    uint32_t key = k[r];
    uint32_t d = (key >> (8 * P)) & 255u;
    uint32_t dest = ldsBase[d] + s - ldsStart[d];
    if (MODE == 0) {
      keyOut[segOff + dest] = key;
      if (wantIdx) idxOut[segOff + dest] = idxIn[segOff + blkBase + pr[r]];
    } else if (MODE == 1) {
      tsorted[dest] = finv(key);
    } else {
      uint32_t gidx = idxIn[segOff + blkBase + pr[r]];
      out[(size_t)(seg - 1) * SEG_N + gidx] = tsorted[dest];
    }
  }
}

// ---------------------------------------------------------------------------
extern "C" void kernel_launch(void* const* d_in, const int* in_sizes, int n_in,
                              void* d_out, int out_size, void* d_ws, size_t ws_size,
                              hipStream_t stream) {
  const float* x = (const float*)d_in[0];
  const float* tmpl = (const float*)d_in[1];
  float* out = (float*)d_out;

  auto need = [](int nb) -> size_t {
    return (size_t)nb * ((size_t)SEG_N * 16 + (size_t)HL * 8 + 256) +
           (size_t)SEG_N * 4 + 8192;
  };
  const int nb = (ws_size >= need(9)) ? 9 : (ws_size >= need(3)) ? 3 : 1;

  uint8_t* w = (uint8_t*)d_ws;
  size_t off = 0;
  auto carve = [&](size_t bytes) -> void* {
    void* p = w + off;
    off = (off + bytes + 255) & ~(size_t)255;
    return p;
  };
  uint32_t* keyA = (uint32_t*)carve((size_t)nb * SEG_N * 4);
  uint32_t* keyB = (uint32_t*)carve((size_t)nb * SEG_N * 4);
  uint32_t* idxA = (uint32_t*)carve((size_t)nb * SEG_N * 4);
  uint32_t* idxB = (uint32_t*)carve((size_t)nb * SEG_N * 4);
  uint32_t* Hkb = (uint32_t*)carve((size_t)nb * HL * 4);
  uint32_t* Hbk = (uint32_t*)carve((size_t)nb * HL * 4);
  uint32_t* partials = (uint32_t*)carve((size_t)nb * 64 * 4);
  float* tsorted = (float*)carve((size_t)SEG_N * 4);

  for (int g = 0; g < NSEG; g += nb) {
    const dim3 gi(NBLK, nb);
    const dim3 gt(40, nb);
    const dim3 gs(SNB, nb);
    const dim3 g1(1, nb);

    auto scan_h = [&]() {
      transp_k<<<gt, 256, 0, stream>>>(Hkb, Hbk);
      scan_a_k<<<gs, 256, 0, stream>>>(Hbk, partials);
      scan_b_k<<<g1, 256, 0, stream>>>(partials);
      scan_c_k<<<gs, 256, 0, stream>>>(Hbk, partials);
    };

    // pass 0 (digit-0 hist fused into init)
    init_k<<<gi, 256, 0, stream>>>(x, tmpl, g, keyA, idxA, Hkb);
    scan_h();
    part_k<0, 0><<<gi, 256, 0, stream>>>(keyA, idxA, keyB, idxB, Hbk,
                                         tsorted, out, g, 0);
    // pass 1
    hist_k<<<gi, 256, 0, stream>>>(keyB, Hkb, 1);
    scan_h();
    part_k<1, 0><<<gi, 256, 0, stream>>>(keyB, idxB, keyA, idxA, Hbk,
                                         tsorted, out, g, 0);
    // pass 2
    hist_k<<<gi, 256, 0, stream>>>(keyA, Hkb, 2);
    scan_h();
    part_k<2, 0><<<gi, 256, 0, stream>>>(keyA, idxA, keyB, idxB, Hbk,
                                         tsorted, out, g, 0);
    // pass 3 (fused epilogue)
    hist_k<<<gi, 256, 0, stream>>>(keyB, Hkb, 3);
    scan_h();
    if (g == 0) {
      part_k<3, 1><<<dim3(NBLK, 1), 256, 0, stream>>>(keyB, idxB, keyA, idxA,
                                                      Hbk, tsorted, out, g, 0);
      if (nb > 1)
        part_k<3, 2><<<dim3(NBLK, nb - 1), 256, 0, stream>>>(
            keyB, idxB, keyA, idxA, Hbk, tsorted, out, g, 1);
    } else {
      part_k<3, 2><<<dim3(NBLK, nb), 256, 0, stream>>>(
          keyB, idxB, keyA, idxA, Hbk, tsorted, out, g, 0);
    }
  }
}

// Round 5
// 1162.496 us; speedup vs baseline: 3.8344x; 1.0074x over previous
//
#include <hip/hip_runtime.h>
#include <stdint.h>

// HistMatching via stable LSD radix sort (4 x 8-bit passes) of (key32,idx32)
// u64 pairs per segment. Stability via per-(bin,block) histogram matrix +
// exclusive scan. Final pass fuses the epilogue: template -> tsorted[dest]=val;
// samples -> out[idx]=tsorted[dest].
//
// R1: single-LDS-buffer in-place split, run-boundary starts, hoisted bases.
// R2 (REVERTED): per-element global atomics for fused hist (+575us/pass).
// R3 (REVERTED): onesweep — tile-hist LDS atomics on skewed digits too slow.
// R4 (REVERTED): SoA keys/idx — split scattered writes regressed part_k;
//     L3 absorbs pair re-reads so nominal read savings don't materialize.
// R5: (a) part_k split rounds 4x2-bit -> 2x4-bit: halves LDS element
//     movement and barriers. 16-bucket counters: counts u8x4-packed in u32
//     (cntW[4], runtime-indexed like R1's verified cnt[4]); positions
//     u16x4-packed in u64 (posW[4]). (b) transp+scan_a/b/c (4 dispatches)
//     -> ONE scanT_k: gather-transposed read of Hkb (L3-resident) + block
//     scan + decoupled lookback over 40 chunks/segment (360 blocks, all
//     co-resident => spin-safe). 25 -> 15 dispatches per run.

#define SEG_N 2621440            // 128*160*128
#define NSEG 9                   // template + 8 samples
#define TILE 4096
#define NBLK (SEG_N / TILE)      // 640 blocks per segment
#define RADIX 256
#define HL (RADIX * NBLK)        // 163840 histogram-matrix entries per seg
#define SCHUNK 4096
#define SNB (HL / SCHUNK)        // 40 scan chunks per seg
#define SBUF (TILE + (TILE >> 4))  // 4352 u64, padded 1-per-16

// monotone f32 -> u32 (order-preserving)
__device__ __forceinline__ uint32_t fkey(float f) {
  uint32_t b = __float_as_uint(f);
  return b ^ ((b & 0x80000000u) ? 0xFFFFFFFFu : 0x80000000u);
}
__device__ __forceinline__ float finv(uint32_t u) {
  uint32_t b = u ^ ((u & 0x80000000u) ? 0x80000000u : 0xFFFFFFFFu);
  return __uint_as_float(b);
}
__device__ __forceinline__ uint32_t SIDX(uint32_t i) { return i + (i >> 4); }

// ---------- init: build pairsA in index order + digit-0 histogram ----------
__global__ __launch_bounds__(256) void init_k(const float* __restrict__ x,
                                              const float* __restrict__ tmpl,
                                              int segbase,
                                              uint64_t* __restrict__ pairsA,
                                              uint32_t* __restrict__ Hkb) {
  __shared__ uint32_t hw[4 * RADIX];   // per-wave replicated
  const int t = threadIdx.x;
  const int blk = blockIdx.x;
  const int sl = blockIdx.y;
  const int seg = segbase + sl;
  const float* src = (seg == 0) ? tmpl : (x + (size_t)(seg - 1) * SEG_N);
  uint64_t* pa = pairsA + (size_t)sl * SEG_N;
  hw[t] = 0; hw[t + 256] = 0; hw[t + 512] = 0; hw[t + 768] = 0;
  __syncthreads();
  const int w = t >> 6;
  const uint32_t base = blk * TILE;
  const float4* s4 = reinterpret_cast<const float4*>(src + base);
#pragma unroll
  for (int r = 0; r < 4; ++r) {
    float4 v = s4[r * 256 + t];
    uint32_t i0 = base + (uint32_t)(r * 256 + t) * 4u;
    float f[4] = {v.x, v.y, v.z, v.w};
#pragma unroll
    for (int c = 0; c < 4; ++c) {
      uint32_t k = fkey(f[c]);
      atomicAdd(&hw[w * 256 + (k & 255u)], 1u);
      pa[i0 + c] = ((uint64_t)k << 32) | (uint64_t)(i0 + c);
    }
  }
  __syncthreads();
  Hkb[(size_t)sl * HL + (size_t)blk * RADIX + t] =
      hw[t] + hw[t + 256] + hw[t + 512] + hw[t + 768];   // [blk][bin]
}

// ---------- histogram of digit p over current pairs ----------
__global__ __launch_bounds__(256) void hist_k(const uint64_t* __restrict__ pairs,
                                              uint32_t* __restrict__ Hkb, int p) {
  __shared__ uint32_t hw[4 * RADIX];   // per-wave replicated
  const int t = threadIdx.x;
  const int blk = blockIdx.x;
  const int sl = blockIdx.y;
  hw[t] = 0; hw[t + 256] = 0; hw[t + 512] = 0; hw[t + 768] = 0;
  __syncthreads();
  const int w = t >> 6;
  const int sh = 32 + 8 * p;
  const ulonglong2* pc = reinterpret_cast<const ulonglong2*>(
      pairs + (size_t)sl * SEG_N + (size_t)blk * TILE);
#pragma unroll
  for (int r = 0; r < 8; ++r) {
    ulonglong2 v = pc[r * 256 + t];
    atomicAdd(&hw[w * 256 + ((uint32_t)(v.x >> sh) & 255u)], 1u);
    atomicAdd(&hw[w * 256 + ((uint32_t)(v.y >> sh) & 255u)], 1u);
  }
  __syncthreads();
  Hkb[(size_t)sl * HL + (size_t)blk * RADIX + t] =
      hw[t] + hw[t + 256] + hw[t + 512] + hw[t + 768];
}

// ---------- fused transpose-read + 3-level scan via decoupled lookback ----
// Scans the conceptual transposed sequence e=bin*NBLK+blk (exclusive) from
// Hkb [blk][bin] into Hbk [bin][blk]. 40 chunks/segment, all blocks
// co-resident (360 total) => flag-spin lookback is deadlock-free.
// desc word = flag[31:30] | value[29:0], relaxed agent-scope.
__global__ __launch_bounds__(256) void scanT_k(const uint32_t* __restrict__ Hkb,
                                               uint32_t* __restrict__ Hbk,
                                               uint32_t* __restrict__ desc) {
  __shared__ uint32_t lds[256];
  __shared__ uint32_t baseS;
  const int t = threadIdx.x;
  const int c = blockIdx.x;          // 0..SNB-1
  const int sl = blockIdx.y;
  const uint32_t* src = Hkb + (size_t)sl * HL;
  const uint32_t e0 = (uint32_t)c * SCHUNK + (uint32_t)t * 16;
  uint32_t vals[16];
  uint32_t s = 0;
#pragma unroll
  for (int i = 0; i < 16; ++i) {
    uint32_t e = e0 + (uint32_t)i;
    uint32_t bin = e / NBLK, blk = e - bin * NBLK;
    vals[i] = src[(size_t)blk * RADIX + bin];
    s += vals[i];
  }
  // block-wide exclusive scan of per-thread sums (Hillis-Steele)
  lds[t] = s;
  __syncthreads();
#pragma unroll
  for (int off = 1; off < 256; off <<= 1) {
    uint32_t a = (t >= off) ? lds[t - off] : 0u;
    __syncthreads();
    lds[t] += a;
    __syncthreads();
  }
  const uint32_t incl = lds[t];
  const uint32_t total = lds[255];
  const uint32_t ex = incl - s;

  uint32_t* dseg = desc + sl * SNB;
  if (t == 0) {
    __hip_atomic_store(&dseg[c], (total & 0x3FFFFFFFu) |
                                     ((c == 0 ? 2u : 1u) << 30),
                       __ATOMIC_RELAXED, __HIP_MEMORY_SCOPE_AGENT);
    uint32_t acc = 0;
    if (c > 0) {
      int b = c - 1;
      for (;;) {
        uint32_t v;
        do {
          v = __hip_atomic_load(&dseg[b], __ATOMIC_RELAXED,
                                __HIP_MEMORY_SCOPE_AGENT);
        } while ((v >> 30) == 0u);
        acc += v & 0x3FFFFFFFu;
        if ((v >> 30) == 2u) break;
        --b;
      }
      __hip_atomic_store(&dseg[c], ((acc + total) & 0x3FFFFFFFu) | (2u << 30),
                         __ATOMIC_RELAXED, __HIP_MEMORY_SCOPE_AGENT);
    }
    baseS = acc;
  }
  __syncthreads();
  uint32_t run = baseS + ex;
  uint32_t* dst = Hbk + (size_t)sl * HL + e0;
#pragma unroll
  for (int i = 0; i < 16; ++i) {
    dst[i] = run;
    run += vals[i];
  }
}

// ---------- stable partition pass (templated digit P, output MODE) ----------
// MODE 0: write pairs to dst; MODE 1: tsorted[dest]=val; MODE 2: out[idx]=tsorted[dest]
// Split: 2 rounds of 4-bit (16 buckets). Counters: counts packed u8x4 in
// cntW[4] (runtime-indexed 4-word array, same promotion pattern as R1's
// cnt[4]); positions packed u16x4 in posW[4] u64. Max field value 4096 ->
// no overflow in either packing.
template <int P, int MODE>
__global__ __launch_bounds__(256) void part_k(const uint64_t* __restrict__ src,
                                              uint64_t* __restrict__ dst,
                                              const uint32_t* __restrict__ Hbk,
                                              float* __restrict__ tsorted,
                                              float* __restrict__ out,
                                              int segbase, int slbase) {
  __shared__ uint64_t buf[SBUF];       // single tile buffer (in-place split)
  __shared__ uint32_t ldsStart[RADIX];
  __shared__ uint32_t ldsBase[RADIX];
  __shared__ uint32_t scanS[48];       // [0..31] wave sums/offs, [32..39] bases
  const int t = threadIdx.x;
  const int blk = blockIdx.x;
  const int sl = slbase + blockIdx.y;
  const int seg = segbase + sl;
  const uint64_t* ps = src + (size_t)sl * SEG_N + (size_t)blk * TILE;

  // hoisted: per-digit global base (uncoalesced gather; latency hides under
  // the sort rounds — first consumer is the emit loop at the end)
  ldsBase[t] = Hbk[(size_t)sl * HL + (size_t)t * NBLK + blk];

  // stage tile into LDS (coalesced), padded layout
#pragma unroll
  for (int r = 0; r < 16; ++r) buf[SIDX(r * 256 + t)] = ps[r * 256 + t];
  __syncthreads();

  // 2 stable 4-bit split rounds (low nibble first), IN PLACE: every thread
  // reads its 16 elements into registers BEFORE the first barrier; all
  // scatter writes happen AFTER the last pre-scatter barrier.
  uint64_t e[16];
  const int lane = t & 63, w = t >> 6;
#pragma unroll
  for (int rnd = 0; rnd < 2; ++rnd) {
    const int sh = 32 + 8 * P + 4 * rnd;
#pragma unroll
    for (int j = 0; j < 16; ++j) e[j] = buf[SIDX(t * 16 + j)];
    uint32_t cntW[4] = {0u, 0u, 0u, 0u};
#pragma unroll
    for (int j = 0; j < 16; ++j) {
      uint32_t d4 = (uint32_t)(e[j] >> sh) & 15u;
      cntW[d4 >> 2] += 1u << ((d4 & 3u) * 8u);
    }
    // unpack to 8 u16-pair words: v[q] = counts of buckets (2q, 2q+1)
    uint32_t v[8], a[8];
#pragma unroll
    for (int q = 0; q < 8; ++q) {
      uint32_t word = cntW[q >> 1];
      uint32_t s2 = (q & 1) * 16;
      v[q] = ((word >> s2) & 0xffu) | (((word >> (s2 + 8)) & 0xffu) << 16);
      a[q] = v[q];
    }
    // wave-inclusive scan of all 8 packed words
#pragma unroll
    for (int o = 1; o < 64; o <<= 1) {
#pragma unroll
      for (int q = 0; q < 8; ++q) {
        uint32_t n = __shfl_up(a[q], (unsigned)o, 64);
        if (lane >= o) a[q] += n;
      }
    }
    if (lane == 63) {
#pragma unroll
      for (int q = 0; q < 8; ++q) scanS[w * 8 + q] = a[q];
    }
    __syncthreads();
    if (t == 0) {
      // per-word exclusive wave offsets + 16-bucket base prefix
      uint32_t run = 0;
#pragma unroll
      for (int q = 0; q < 8; ++q) {
        uint32_t r0 = 0;
#pragma unroll
        for (int ww = 0; ww < 4; ++ww) {
          uint32_t xv = scanS[ww * 8 + q];
          scanS[ww * 8 + q] = r0;
          r0 += xv;
        }
        uint32_t b0 = r0 & 0xffffu, b1 = r0 >> 16;
        scanS[32 + q] = run | ((run + b0) << 16);
        run += b0 + b1;
      }
    }
    __syncthreads();
    // per-thread running positions, u16x4 packed per hi-nibble word
    uint64_t posW[4];
#pragma unroll
    for (int q = 0; q < 8; ++q) {
      uint32_t exq = a[q] - v[q] + scanS[w * 8 + q];
      uint32_t base = scanS[32 + q];
      uint32_t p0 = (base & 0xffffu) + (exq & 0xffffu);
      uint32_t p1 = (base >> 16) + (exq >> 16);
      uint64_t pk = (uint64_t)p0 | ((uint64_t)p1 << 16);
      if ((q & 1) == 0) posW[q >> 1] = pk;
      else posW[q >> 1] |= pk << 32;
    }
#pragma unroll
    for (int j = 0; j < 16; ++j) {
      uint32_t d4 = (uint32_t)(e[j] >> sh) & 15u;
      uint32_t hi = d4 >> 2;
      uint32_t fs = (d4 & 3u) * 16u;
      uint32_t p = (uint32_t)(posW[hi] >> fs) & 0xffffu;
      posW[hi] += (uint64_t)1 << fs;
      buf[SIDX(p)] = e[j];
    }
    __syncthreads();
  }
  // buf: tile stably sorted by digit P

  // per-digit local starts via sorted-run boundary detection
  const uint8_t* b8 = reinterpret_cast<const uint8_t*>(buf);
#pragma unroll
  for (int r = 0; r < 16; ++r) {
    uint32_t s = (uint32_t)(r * 256 + t);
    e[r] = buf[SIDX(s)];
    uint32_t d = (uint32_t)(e[r] >> (32 + 8 * P)) & 255u;
    uint32_t dp = (s == 0) ? 0x100u
                           : (uint32_t)b8[(size_t)SIDX(s - 1) * 8 + 4 + P];
    if (d != dp) ldsStart[d] = s;
  }
  __syncthreads();

  // emit in sorted-tile order: digit runs -> contiguous global ranges
#pragma unroll
  for (int r = 0; r < 16; ++r) {
    uint32_t s = (uint32_t)(r * 256 + t);
    uint64_t el = e[r];
    uint32_t key = (uint32_t)(el >> 32);
    uint32_t d = (key >> (8 * P)) & 255u;
    uint32_t dest = ldsBase[d] + s - ldsStart[d];
    if (MODE == 0) {
      dst[(size_t)sl * SEG_N + dest] = el;
    } else if (MODE == 1) {
      tsorted[dest] = finv(key);
    } else {
      out[(size_t)(seg - 1) * SEG_N + (uint32_t)el] = tsorted[dest];
    }
  }
}

// ---------------------------------------------------------------------------
extern "C" void kernel_launch(void* const* d_in, const int* in_sizes, int n_in,
                              void* d_out, int out_size, void* d_ws, size_t ws_size,
                              hipStream_t stream) {
  const float* x = (const float*)d_in[0];
  const float* tmpl = (const float*)d_in[1];
  float* out = (float*)d_out;

  auto need = [](int nb) -> size_t {
    return (size_t)nb * ((size_t)SEG_N * 16 + (size_t)HL * 8 + 4096) +
           (size_t)SEG_N * 4 + 16384;
  };
  const int nb = (ws_size >= need(9)) ? 9 : (ws_size >= need(3)) ? 3 : 1;

  uint8_t* w = (uint8_t*)d_ws;
  size_t off = 0;
  auto carve = [&](size_t bytes) -> void* {
    void* p = w + off;
    off = (off + bytes + 255) & ~(size_t)255;
    return p;
  };
  uint64_t* pairsA = (uint64_t*)carve((size_t)nb * SEG_N * 8);
  uint64_t* pairsB = (uint64_t*)carve((size_t)nb * SEG_N * 8);
  uint32_t* Hkb = (uint32_t*)carve((size_t)nb * HL * 4);
  uint32_t* Hbk = (uint32_t*)carve((size_t)nb * HL * 4);
  uint32_t* desc = (uint32_t*)carve((size_t)4 * nb * SNB * 4);
  float* tsorted = (float*)carve((size_t)SEG_N * 4);

  for (int g = 0; g < NSEG; g += nb) {
    const dim3 gi(NBLK, nb);
    const dim3 gs(SNB, nb);

    hipMemsetAsync(desc, 0, (size_t)4 * nb * SNB * 4, stream);

    // pass 0 (digit-0 hist fused into init)
    init_k<<<gi, 256, 0, stream>>>(x, tmpl, g, pairsA, Hkb);
    scanT_k<<<gs, 256, 0, stream>>>(Hkb, Hbk, desc + 0 * nb * SNB);
    part_k<0, 0><<<gi, 256, 0, stream>>>(pairsA, pairsB, Hbk, tsorted, out, g, 0);
    // pass 1
    hist_k<<<gi, 256, 0, stream>>>(pairsB, Hkb, 1);
    scanT_k<<<gs, 256, 0, stream>>>(Hkb, Hbk, desc + 1 * nb * SNB);
    part_k<1, 0><<<gi, 256, 0, stream>>>(pairsB, pairsA, Hbk, tsorted, out, g, 0);
    // pass 2
    hist_k<<<gi, 256, 0, stream>>>(pairsA, Hkb, 2);
    scanT_k<<<gs, 256, 0, stream>>>(Hkb, Hbk, desc + 2 * nb * SNB);
    part_k<2, 0><<<gi, 256, 0, stream>>>(pairsA, pairsB, Hbk, tsorted, out, g, 0);
    // pass 3 (fused epilogue)
    hist_k<<<gi, 256, 0, stream>>>(pairsB, Hkb, 3);
    scanT_k<<<gs, 256, 0, stream>>>(Hkb, Hbk, desc + 3 * nb * SNB);
    if (g == 0) {
      part_k<3, 1><<<dim3(NBLK, 1), 256, 0, stream>>>(pairsB, pairsA, Hbk,
                                                      tsorted, out, g, 0);
      if (nb > 1)
        part_k<3, 2><<<dim3(NBLK, nb - 1), 256, 0, stream>>>(pairsB, pairsA, Hbk,
                                                             tsorted, out, g, 1);
    } else {
      part_k<3, 2><<<dim3(NBLK, nb), 256, 0, stream>>>(pairsB, pairsA, Hbk,
                                                       tsorted, out, g, 0);
    }
  }
}